// Round 1
// baseline (810.195 us; speedup 1.0000x reference)
//
#include <hip/hip_runtime.h>
#include <math.h>

#define C0f        299792458.0f
#define ALPHA_LINf 2.3025850929940458e-4f   // 1e-3 * ln(10)/10

#define NP    4          // num_pumps
#define MD    4          // modes
#define NC    100        // num_channels
#define NF    104        // NP + NC
#define FM    416        // NF * MD
#define GPAD  108        // padded row stride (dwords): 2-way-max bank aliasing, 16B aligned
#define NT    448        // 7 waves
#define RRMAX 801

__global__ __launch_bounds__(NT, 4)
void raman_kernel(const float* __restrict__ x,
                  const float* __restrict__ sig_freq,
                  const float* __restrict__ sig_pow,
                  const float* __restrict__ sig_loss,
                  const float* __restrict__ loss_coef,
                  const float* __restrict__ overlap,
                  const float* __restrict__ raman,
                  const int*   __restrict__ steps_p,
                  const float* __restrict__ length_p,
                  const float* __restrict__ maxf_p,
                  float* __restrict__ out,
                  int L)
{
    __shared__ __align__(16) float gain[NF][GPAD];   // 44928 B
    __shared__ __align__(16) float Qt[MD][GPAD];     // 1728 B
    __shared__ __align__(16) float Xl[FM];           // 1664 B
    __shared__ float rr[RRMAX + 1];                  // 3208 B
    __shared__ float ff[NF];                         // 416 B

    const int t  = threadIdx.x;
    const int b  = blockIdx.x;
    const int i4 = t >> 2;   // frequency index (matvec) / j-group (Qt build)
    const int mi = t & 3;    // mode index

    // ---- stage Raman response LUT and frequency vector ----
    for (int i = t; i < L && i < RRMAX + 1; i += NT) rr[i] = raman[i];
    if (t < NF) {
        ff[t] = (t < NP) ? (C0f / x[b * 20 + t]) : sig_freq[t - NP];
    }
    __syncthreads();

    // ---- build frequency-level gain matrix (104x104) ----
    const float maxf = maxf_p[0];
    const float Lm1  = (float)(L - 1);
    for (int idx = t; idx < NF * NF; idx += NT) {
        int i = idx / NF;
        int j = idx - i * NF;
        float fi = ff[i], fj = ff[j];
        float fd = fj - fi;                       // f_j - f_i
        float pos = fabsf(fd) / maxf * Lm1;
        int i0 = (int)pos;                        // pos >= 0: trunc == floor
        if (i0 > L - 2) i0 = L - 2;
        float w = pos - (float)i0;
        float g = rr[i0] * (1.0f - w) + rr[i0 + 1] * w;
        if (fd < 0.0f) g = -g;                    // antisymmetric gain/depletion
        float sc = fi / fj;                       // photon-number scaling
        g *= (sc > 1.0f) ? sc : 1.0f;
        gain[i][j] = g;
    }

    // ---- per-thread persistent state (element t = i4*4 + mi) ----
    float lossv = 0.0f, Pv = 0.0f;
    float ov0 = 0.0f, ov1 = 0.0f, ov2 = 0.0f, ov3 = 0.0f;
    if (t < FM) {
        ov0 = overlap[mi * MD + 0];
        ov1 = overlap[mi * MD + 1];
        ov2 = overlap[mi * MD + 2];
        ov3 = overlap[mi * MD + 3];
        if (t < NP * MD) {
            float wl_nm = x[b * 20 + i4] * 1e9f;
            lossv = (loss_coef[2] + loss_coef[1] * wl_nm
                     + loss_coef[0] * wl_nm * wl_nm) * ALPHA_LINf;
            Pv = x[b * 20 + NP + t];
        } else {
            lossv = sig_loss[t - NP * MD];
            Pv = sig_pow[t - NP * MD];
        }
        Xl[t] = Pv;
    }

    const int   nstep = steps_p[0] - 1;
    const float h  = length_p[0] / (float)(steps_p[0] - 1);
    const float hh = 0.5f * h;
    const float h6 = h / 6.0f;

    // ode eval on current Xl; returns k for element t.
    // Contract: caller barriers between Xl writes and this call.
    auto ode_eval = [&]() -> float {
        if (t < FM) {
            // Qt[mi][j] = sum_mj O[mi][mj] * X[j*4+mj];  this thread does j = i4
            const float4 xv = *(const float4*)&Xl[i4 * 4];
            Qt[mi][i4] = ov0 * xv.x + ov1 * xv.y + ov2 * xv.z + ov3 * xv.w;
        }
        __syncthreads();
        float k = 0.0f;
        if (t < FM) {
            const float* __restrict__ grow = &gain[i4][0];
            const float* __restrict__ qrow = &Qt[mi][0];
            float a0 = 0.0f, a1 = 0.0f, a2 = 0.0f, a3 = 0.0f;
#pragma unroll
            for (int j = 0; j < NF; j += 8) {
                float4 g0 = *(const float4*)(grow + j);
                float4 g1 = *(const float4*)(grow + j + 4);
                float4 q0 = *(const float4*)(qrow + j);
                float4 q1 = *(const float4*)(qrow + j + 4);
                a0 += g0.x * q0.x; a1 += g0.y * q0.y;
                a2 += g0.z * q0.z; a3 += g0.w * q0.w;
                a0 += g1.x * q1.x; a1 += g1.y * q1.y;
                a2 += g1.z * q1.z; a3 += g1.w * q1.w;
            }
            float acc = (a0 + a1) + (a2 + a3);
            k = (acc - lossv) * Xl[t];
        }
        return k;
    };

    float accv = 0.0f;
    for (int s = 0; s < nstep; ++s) {
        __syncthreads();                 // Xl(P) visible; prior Qt reads done
        float k1 = ode_eval();
        if (t < FM) { accv = k1;          Xl[t] = Pv + hh * k1; }
        __syncthreads();
        float k2 = ode_eval();
        if (t < FM) { accv += 2.0f * k2;  Xl[t] = Pv + hh * k2; }
        __syncthreads();
        float k3 = ode_eval();
        if (t < FM) { accv += 2.0f * k3;  Xl[t] = Pv + h  * k3; }
        __syncthreads();
        float k4 = ode_eval();
        if (t < FM) { accv += k4; Pv += h6 * accv; Xl[t] = Pv; }
    }

    // ---- write signal spectrum: (B, NC, MD), drop pumps ----
    if (t >= NP * MD && t < FM) {
        out[b * (NC * MD) + (t - NP * MD)] = Pv;
    }
}

extern "C" void kernel_launch(void* const* d_in, const int* in_sizes, int n_in,
                              void* d_out, int out_size, void* d_ws, size_t ws_size,
                              hipStream_t stream) {
    const float* x   = (const float*)d_in[0];
    const float* sf  = (const float*)d_in[1];
    const float* sp  = (const float*)d_in[2];
    const float* sl  = (const float*)d_in[3];
    const float* lc  = (const float*)d_in[4];
    const float* ov  = (const float*)d_in[5];
    const float* rrp = (const float*)d_in[6];
    const int*   stp = (const int*)d_in[10];
    const float* len = (const float*)d_in[11];
    const float* mxf = (const float*)d_in[12];

    const int B = in_sizes[0] / (NP * (1 + MD));   // 512
    const int L = in_sizes[6];                     // 801

    raman_kernel<<<dim3(B), dim3(NT), 0, stream>>>(
        x, sf, sp, sl, lc, ov, rrp, stp, len, mxf, (float*)d_out, L);
}

// Round 2
// 745.735 us; speedup vs baseline: 1.0864x; 1.0864x over previous
//
#include <hip/hip_runtime.h>
#include <math.h>

#define C0f        299792458.0f
#define ALPHA_LINf 2.3025850929940458e-4f   // 1e-3 * ln(10)/10

#define NP    4          // num_pumps
#define MD    4          // modes
#define NC    100        // num_channels
#define NF    104        // NP + NC
#define FM    416        // NF * MD
#define XPAD  108        // padded row stride (dwords) for Xt
#define NT    448        // 7 full waves
#define RRSZ  801

// quad-broadcast lane q (within each group of 4 lanes) via DPP quad_perm — VALU pipe
template <int Q>
__device__ __forceinline__ float qbcast(float v) {
    int r = __builtin_amdgcn_mov_dpp(__float_as_int(v), Q * 0x55, 0xF, 0xF, true);
    return __int_as_float(r);
}

__global__ __launch_bounds__(NT, 3)   // cap ~170 VGPR, avoid spill
void raman_kernel(const float* __restrict__ x,
                  const float* __restrict__ sig_freq,
                  const float* __restrict__ sig_pow,
                  const float* __restrict__ sig_loss,
                  const float* __restrict__ loss_coef,
                  const float* __restrict__ overlap,
                  const float* __restrict__ raman,
                  const int*   __restrict__ steps_p,
                  const float* __restrict__ length_p,
                  const float* __restrict__ maxf_p,
                  float* __restrict__ out,
                  int L)
{
    __shared__ float rr[RRSZ + 1];                 // Raman LUT
    __shared__ float ff[NF];                       // frequencies
    __shared__ __align__(16) float Xt[2][MD][XPAD]; // double-buffered transposed state

    const int t  = threadIdx.x;
    const int b  = blockIdx.x;
    const int i  = (t >> 2) < NF ? (t >> 2) : (NF - 1);  // frequency index (clamped for tail threads)
    const int mi = t & 3;                                 // mode index

    // ---- stage LUT + frequency vector ----
    for (int k = t; k < L && k <= RRSZ; k += NT) rr[k] = raman[k];
    if (t < NF) {
        ff[t] = (t < NP) ? (C0f / x[b * 20 + t]) : sig_freq[t - NP];
    }
    __syncthreads();

    // ---- per-thread gain row in REGISTERS: g[j] = gain[i][j] ----
    const float maxf  = maxf_p[0];
    const float scale = (float)(L - 1) / maxf;
    const float fi    = ff[i];
    float g[NF];
#pragma unroll
    for (int j = 0; j < NF; ++j) {
        float fj  = ff[j];
        float fd  = fj - fi;                  // f_j - f_i
        float pos = fabsf(fd) * scale;
        int i0 = (int)pos;                    // pos >= 0 → trunc == floor
        if (i0 > L - 2) i0 = L - 2;
        float w  = pos - (float)i0;
        float gg = rr[i0] * (1.0f - w) + rr[i0 + 1] * w;
        if (fd < 0.0f) gg = -gg;              // antisymmetric
        float sc = fi / fj;                   // photon-number scaling
        g[j] = gg * fmaxf(1.0f, sc);
    }

    // ---- per-thread state ----
    float lossv = 0.0f, Pv = 0.0f;
    float ov0, ov1, ov2, ov3;
    ov0 = overlap[mi * MD + 0];
    ov1 = overlap[mi * MD + 1];
    ov2 = overlap[mi * MD + 2];
    ov3 = overlap[mi * MD + 3];
    if (t < FM) {
        if (t < NP * MD) {
            float wl_nm = x[b * 20 + i] * 1e9f;
            lossv = (loss_coef[2] + loss_coef[1] * wl_nm
                     + loss_coef[0] * wl_nm * wl_nm) * ALPHA_LINf;
            Pv = x[b * 20 + NP + t];
        } else {
            lossv = sig_loss[t - NP * MD];
            Pv = sig_pow[t - NP * MD];
        }
    }

    const int   nstep = steps_p[0] - 1;
    const float h  = length_p[0] / (float)(steps_p[0] - 1);
    const float hh = 0.5f * h;
    const float h6 = h / 6.0f;

    // one ODE eval: S = g . Xt[buf][mi][*]; quad-combine with overlap row; k = (R - loss)*Xs
    auto ode_eval = [&](float Xs, int buf) -> float {
        if (t < FM) Xt[buf][mi][i] = Xs;
        __syncthreads();
        const float* __restrict__ xr = &Xt[buf][mi][0];
        float a0 = 0.0f, a1 = 0.0f, a2 = 0.0f, a3 = 0.0f;
#pragma unroll
        for (int j = 0; j < NF; j += 8) {
            float4 x0 = *(const float4*)(xr + j);
            float4 x1 = *(const float4*)(xr + j + 4);
            a0 += g[j + 0] * x0.x; a1 += g[j + 1] * x0.y;
            a2 += g[j + 2] * x0.z; a3 += g[j + 3] * x0.w;
            a0 += g[j + 4] * x1.x; a1 += g[j + 5] * x1.y;
            a2 += g[j + 6] * x1.z; a3 += g[j + 7] * x1.w;
        }
        float S = (a0 + a1) + (a2 + a3);       // S[i, mi]
        // R[i,mi] = sum_mj O[mi][mj] * S[i][mj]  (cross-quad via DPP)
        float s0 = qbcast<0>(S);
        float s1 = qbcast<1>(S);
        float s2 = qbcast<2>(S);
        float s3 = qbcast<3>(S);
        float R = ov0 * s0 + ov1 * s1 + ov2 * s2 + ov3 * s3;
        return (R - lossv) * Xs;
    };

    for (int s = 0; s < nstep; ++s) {
        float k1 = ode_eval(Pv, 0);
        float k2 = ode_eval(Pv + hh * k1, 1);
        float k3 = ode_eval(Pv + hh * k2, 0);
        float k4 = ode_eval(Pv + h  * k3, 1);
        Pv += h6 * (k1 + 2.0f * k2 + 2.0f * k3 + k4);
    }

    // ---- write signal spectrum: (B, NC, MD), pumps dropped ----
    if (t >= NP * MD && t < FM) {
        out[b * (NC * MD) + (t - NP * MD)] = Pv;
    }
}

extern "C" void kernel_launch(void* const* d_in, const int* in_sizes, int n_in,
                              void* d_out, int out_size, void* d_ws, size_t ws_size,
                              hipStream_t stream) {
    const float* x   = (const float*)d_in[0];
    const float* sf  = (const float*)d_in[1];
    const float* sp  = (const float*)d_in[2];
    const float* sl  = (const float*)d_in[3];
    const float* lc  = (const float*)d_in[4];
    const float* ov  = (const float*)d_in[5];
    const float* rrp = (const float*)d_in[6];
    const int*   stp = (const int*)d_in[10];
    const float* len = (const float*)d_in[11];
    const float* mxf = (const float*)d_in[12];

    const int B = in_sizes[0] / (NP * (1 + MD));   // 512
    const int L = in_sizes[6];                     // 801

    raman_kernel<<<dim3(B), dim3(NT), 0, stream>>>(
        x, sf, sp, sl, lc, ov, rrp, stp, len, mxf, (float*)d_out, L);
}

// Round 3
// 410.250 us; speedup vs baseline: 1.9749x; 1.8178x over previous
//
#include <hip/hip_runtime.h>
#include <math.h>

#define C0f        299792458.0f
#define ALPHA_LINf 2.3025850929940458e-4f   // 1e-3 * ln(10)/10

#define NP   4          // num_pumps
#define MD   4          // modes
#define NC   100        // num_channels
#define NF   104        // NP + NC
#define FM   416        // NF * MD
#define NT   256        // 4 waves
#define NACT 208        // 52 freq-quads * 4 threads
#define RRSZ 801

// v + quad_perm<IMM>(v): DPP cross-lane add within each quad (VALU pipe, not LDS)
template <int IMM>
__device__ __forceinline__ float dpp_add(float v) {
    int r = __builtin_amdgcn_mov_dpp(__float_as_int(v), IMM, 0xF, 0xF, true);
    return v + __int_as_float(r);
}
#define QUAD_ALLRED(s) do { s = dpp_add<0xB1>(s); s = dpp_add<0x4E>(s); } while (0)

__global__ __launch_bounds__(NT, 2)   // generous VGPR cap (256) — grid fixes 2 blocks/CU anyway
void raman_kernel(const float* __restrict__ x,
                  const float* __restrict__ sig_freq,
                  const float* __restrict__ sig_pow,
                  const float* __restrict__ sig_loss,
                  const float* __restrict__ loss_coef,
                  const float* __restrict__ overlap,
                  const float* __restrict__ raman,
                  const int*   __restrict__ steps_p,
                  const float* __restrict__ length_p,
                  const float* __restrict__ maxf_p,
                  float* __restrict__ out,
                  int L)
{
    __shared__ float rr[RRSZ + 1];                 // Raman LUT
    __shared__ float ff[NF];                       // frequencies
    __shared__ __align__(16) float Xb[2][FM];      // mode-interleaved state: Xb[buf][4*j+m]

    const int t  = threadIdx.x;
    const int b  = blockIdx.x;
    const int q  = t & 3;                          // j-chunk AND owned mode
    const int u  = t >> 2;                         // freq-pair index, active < 52
    const int ua = (u < 52) ? u : 51;              // clamp for tail threads
    const int i0 = ua;
    const int i1 = ua + 52;
    const bool act = (t < NACT);

    // ---- stage LUT + frequency vector ----
    for (int k = t; k < L && k <= RRSZ; k += NT) rr[k] = raman[k];
    if (t < NF) ff[t] = (t < NP) ? (C0f / x[b * 20 + t]) : sig_freq[t - NP];
    __syncthreads();

    // ---- per-thread gain registers: rows i0,i1 over j-chunk [26q, 26q+26) ----
    const float maxf  = maxf_p[0];
    const float scale = (float)(L - 1) / maxf;
    const float f0 = ff[i0];
    const float f1 = ff[i1];

    auto gain_of = [&](float fi, float fj) -> float {
        float fd  = fj - fi;                       // f_j - f_i
        float pos = fabsf(fd) * scale;
        int idx = (int)pos;                        // pos >= 0: trunc == floor
        if (idx > L - 2) idx = L - 2;
        float w  = pos - (float)idx;
        float gg = rr[idx] * (1.0f - w) + rr[idx + 1] * w;
        gg = (fd < 0.0f) ? -gg : gg;               // antisymmetric
        return gg * fmaxf(1.0f, fi / fj);          // photon-number scaling
    };

    float g0[26], g1[26];
#pragma unroll
    for (int jj = 0; jj < 26; ++jj) {
        float fj = ff[26 * q + jj];
        g0[jj] = gain_of(f0, fj);
        g1[jj] = gain_of(f1, fj);
    }

    // overlap row for owned mode q
    const float Ox = overlap[q * MD + 0];
    const float Oy = overlap[q * MD + 1];
    const float Oz = overlap[q * MD + 2];
    const float Ow = overlap[q * MD + 3];

    // ---- per-thread state: elements e0 = t (= i0*4+q), e1 = t+208 (= i1*4+q) ----
    float loss0 = 0.0f, P0 = 0.0f, loss1 = 0.0f, P1 = 0.0f;
    if (act) {
        if (t < NP * MD) {                         // pump element
            float wl = x[b * 20 + i0] * 1e9f;      // i0 = t>>2 < 4 here
            loss0 = (loss_coef[2] + loss_coef[1] * wl
                     + loss_coef[0] * wl * wl) * ALPHA_LINf;
            P0 = x[b * 20 + NP + t];
        } else {
            loss0 = sig_loss[t - NP * MD];
            P0 = sig_pow[t - NP * MD];
        }
        loss1 = sig_loss[t + NACT - NP * MD];      // e1 >= 208: always signal
        P1 = sig_pow[t + NACT - NP * MD];
    }

    const int   nstep = steps_p[0] - 1;
    const float h  = length_p[0] / (float)(steps_p[0] - 1);
    const float hh = 0.5f * h;
    const float h6 = h / 6.0f;

    // one ODE eval: stage X (interleaved), dot with g regs, DPP quad-allreduce, overlap row
    auto ode_eval = [&](float Xs0, float Xs1, int buf, float& k0, float& k1) {
        if (act) {
            Xb[buf][t] = Xs0;                      // dword t: conflict-free
            Xb[buf][t + NACT] = Xs1;
        }
        __syncthreads();
        const float* __restrict__ xr = &Xb[buf][104 * q];   // 4*(26q) dwords
        float s0x = 0.f, s0y = 0.f, s0z = 0.f, s0w = 0.f;
        float s1x = 0.f, s1y = 0.f, s1z = 0.f, s1w = 0.f;
#pragma unroll
        for (int jj = 0; jj < 26; ++jj) {
            float4 xv = *(const float4*)(xr + 4 * jj);      // ds_read_b128, imm offset
            float a = g0[jj], c = g1[jj];
            s0x += a * xv.x; s0y += a * xv.y; s0z += a * xv.z; s0w += a * xv.w;
            s1x += c * xv.x; s1y += c * xv.y; s1z += c * xv.z; s1w += c * xv.w;
        }
        // quad all-reduce of the 8 partials (sum over j-chunks) — VALU pipe
        QUAD_ALLRED(s0x); QUAD_ALLRED(s0y); QUAD_ALLRED(s0z); QUAD_ALLRED(s0w);
        QUAD_ALLRED(s1x); QUAD_ALLRED(s1y); QUAD_ALLRED(s1z); QUAD_ALLRED(s1w);
        float R0 = Ox * s0x + Oy * s0y + Oz * s0z + Ow * s0w;
        float R1 = Ox * s1x + Oy * s1y + Oz * s1z + Ow * s1w;
        k0 = (R0 - loss0) * Xs0;
        k1 = (R1 - loss1) * Xs1;
    };

    for (int s = 0; s < nstep; ++s) {
        float k10, k11, k20, k21, k30, k31, k40, k41;
        ode_eval(P0,            P1,            0, k10, k11);
        ode_eval(P0 + hh * k10, P1 + hh * k11, 1, k20, k21);
        ode_eval(P0 + hh * k20, P1 + hh * k21, 0, k30, k31);
        ode_eval(P0 + h  * k30, P1 + h  * k31, 1, k40, k41);
        P0 += h6 * (k10 + 2.0f * k20 + 2.0f * k30 + k40);
        P1 += h6 * (k11 + 2.0f * k21 + 2.0f * k31 + k41);
    }

    // ---- write signal spectrum (B, NC, MD): element e maps to out idx e-16 ----
    if (act) {
        if (t >= NP * MD) out[b * (NC * MD) + t - NP * MD] = P0;
        out[b * (NC * MD) + t + NACT - NP * MD] = P1;
    }
}

extern "C" void kernel_launch(void* const* d_in, const int* in_sizes, int n_in,
                              void* d_out, int out_size, void* d_ws, size_t ws_size,
                              hipStream_t stream) {
    const float* x   = (const float*)d_in[0];
    const float* sf  = (const float*)d_in[1];
    const float* sp  = (const float*)d_in[2];
    const float* sl  = (const float*)d_in[3];
    const float* lc  = (const float*)d_in[4];
    const float* ov  = (const float*)d_in[5];
    const float* rrp = (const float*)d_in[6];
    const int*   stp = (const int*)d_in[10];
    const float* len = (const float*)d_in[11];
    const float* mxf = (const float*)d_in[12];

    const int B = in_sizes[0] / (NP * (1 + MD));   // 512
    const int L = in_sizes[6];                     // 801

    raman_kernel<<<dim3(B), dim3(NT), 0, stream>>>(
        x, sf, sp, sl, lc, ov, rrp, stp, len, mxf, (float*)d_out, L);
}